// Round 5
// baseline (136.641 us; speedup 1.0000x reference)
//
#include <hip/hip_runtime.h>
#include <math.h>

#define F 128
#define H 64       // F/2
#define NBMOL 48
#define BATOMS 4   // atoms per block in k_atom (1 atom per thread-column)
#define CAP 256    // LDS chunk capacity in pair kernel
#define SPLIT 16   // blocks per molecule in pair kernel

__device__ __forceinline__ float silu_f(float x) {
    return x / (1.0f + __expf(-x));
}
__device__ __forceinline__ float softplus_f(float x) {
    return fmaxf(x, 0.0f) + log1pf(__expf(-fabsf(x)));
}
__device__ __forceinline__ float frcp(float x) {
    return __builtin_amdgcn_rcpf(x);
}
__device__ __forceinline__ float dot4(float4 a, float4 b) {
    return fmaf(a.x, b.x, fmaf(a.y, b.y, fmaf(a.z, b.z, a.w * b.w)));
}

// Transpose both W1 matrices (F x H -> H x F) into workspace so k_atom threads
// read weight columns as contiguous float4. Also zeroes out[0].
__global__ __launch_bounds__(256) void k_prep(
    const float* __restrict__ qW1, const float* __restrict__ cW1,
    float* __restrict__ wtq, float* __restrict__ wtc,
    float* __restrict__ out)
{
    int idx = blockIdx.x * 256 + threadIdx.x;   // 0..16383
    if (idx == 0) out[0] = 0.0f;
    int net = idx >> 13;
    int e = idx & 8191;
    int h = e >> 7, f = e & 127;
    const float* src = net ? cW1 : qW1;
    float* dst = net ? wtc : wtq;
    dst[e] = src[f * H + h];   // write coalesced, read strided (tiny, L2)
}

// Kernel A v5: thread-per-(atom, hidden). h = tid>>2, al = tid&3 -> every
// wave holds 4 atoms, so NO address is wave-uniform: all loads are per-lane
// vector loads (vmcnt-pipelined, L1/L2-hit). Weight columns contiguous via
// the k_prep transpose. Grid N/4 = 1536 blocks -> 24 waves/CU.
__global__ __launch_bounds__(256, 4) void k_atom(
    const float* __restrict__ h0, const float* __restrict__ h1,
    const int* __restrict__ batch,
    const float* __restrict__ wtq, const float* __restrict__ qb1,
    const float* __restrict__ qW2, const float* __restrict__ qb2,
    const float* __restrict__ wtc, const float* __restrict__ cb1,
    const float* __restrict__ cW2, const float* __restrict__ cb2,
    const float* __restrict__ muW,
    float* __restrict__ q_raw, float* __restrict__ sqc6,
    float* __restrict__ mu,
    int* __restrict__ segstart, int* __restrict__ segend, int N)
{
    const int tid = threadIdx.x;
    const int h  = tid >> 2;          // hidden unit 0..63
    const int al = tid & 3;           // atom lane 0..3
    const int i  = min(blockIdx.x * BATOMS + al, N - 1);

    const float4* __restrict__ xr = (const float4*)(h0 + (size_t)i * F);
    const float4* __restrict__ wq = (const float4*)(wtq + (size_t)h * F);
    const float4* __restrict__ wc = (const float4*)(wtc + (size_t)h * F);

    float zq = qb1[h];
    float zc = cb1[h];
    #pragma unroll 8
    for (int fb = 0; fb < F / 4; ++fb) {
        float4 x = xr[fb];
        float4 a = wq[fb];
        float4 b = wc[fb];
        zq += dot4(x, a);
        zc += dot4(x, b);
    }

    float vq = silu_f(zq) * qW2[h];
    float vc = silu_f(zc) * cW2[h];

    // reduce over h within wave (lane = h*4+al; xor 4/8/16/32 mixes h bits,
    // preserves al) -> every lane holds the 16-h partial for its al
    #pragma unroll
    for (int off = 4; off < 64; off <<= 1) {
        vq += __shfl_xor(vq, off);
        vc += __shfl_xor(vc, off);
    }

    __shared__ float redw[4][2][4];   // [wave][net][al]
    __shared__ float dred[1];         // dummy pad (unused)
    const int w = tid >> 6;
    const int lane = tid & 63;
    if (lane < 4) {
        redw[w][0][lane] = vq;
        redw[w][1][lane] = vc;
    }
    __syncthreads();

    if (tid < 8) {
        int a = tid & 3, net = tid >> 2;
        int ia = blockIdx.x * BATOMS + a;
        if (ia < N) {
            float z = redw[0][net][a] + redw[1][net][a] +
                      redw[2][net][a] + redw[3][net][a];
            if (net == 0) {
                float qv = z + qb2[0];
                q_raw[ia] = qv;
                int b = batch[ia];
                if (ia == 0 || batch[ia - 1] != b) segstart[b] = ia;
                if (ia == N - 1 || batch[ia + 1] != b) segend[b] = ia + 1;
            } else {
                sqc6[ia] = sqrtf(softplus_f(z + cb2[0]));
            }
        }
    }

    // dipole: 12 h1 rows per block (4 atoms x 3 dims); 16-lane slot per row,
    // each lane 8 floats (2 float4), coalesced 512B per row-read.
    const int slot = tid >> 4;        // 0..15 (12 used)
    const int l = tid & 15;
    if (slot < 3 * BATOMS) {
        int row = blockIdx.x * (3 * BATOMS) + slot;   // flat i*3+d
        if (row < 3 * N) {
            const float4* rp = (const float4*)(h1 + (size_t)row * F);
            const float4* mp = (const float4*)muW;
            float pm = dot4(rp[2 * l], mp[2 * l]) +
                       dot4(rp[2 * l + 1], mp[2 * l + 1]);
            #pragma unroll
            for (int off = 1; off < 16; off <<= 1) pm += __shfl_xor(pm, off);
            if (l == 0) mu[row] = pm;
        }
    }
    (void)dred;
}

// Kernel B: pairwise energy. Grid (NBMOL, SPLIT); block 256.
// Mean subtracted per-pair so staging overlaps the mean-reduce. pos/mu packed
// stride-3 (odd stride -> conflict-free LDS).
__global__ __launch_bounds__(256) void k_pair(
    const float* __restrict__ pos,
    const float* __restrict__ q_raw, const float* __restrict__ sqc6,
    const float* __restrict__ mu,
    const int* __restrict__ segstart, const int* __restrict__ segend,
    float* __restrict__ out)
{
    const int b = blockIdx.x;
    const int s = blockIdx.y;
    const int tid = threadIdx.x;
    const int st = segstart[b];
    const int n = segend[b] - st;

    __shared__ float sq[CAP], sc[CAP], sp[3 * CAP], sm[3 * CAP];
    __shared__ float red[4];

    float e_c = 0.f, e_v = 0.f, e_d = 0.f;

    if (n > 1 && n <= CAP) {
        float part = 0.f;
        for (int k = tid; k < n; k += 256) {
            float qv = q_raw[st + k];
            sq[k] = qv; part += qv;
            sc[k] = sqc6[st + k];
        }
        for (int k = tid; k < 3 * n; k += 256) {
            sp[k] = pos[3 * st + k];
            sm[k] = mu[3 * st + k];
        }
        #pragma unroll
        for (int off = 32; off > 0; off >>= 1) part += __shfl_xor(part, off);
        if ((tid & 63) == 0) red[tid >> 6] = part;
        __syncthreads();
        const float mean = (red[0] + red[1] + red[2] + red[3]) / (float)n;

        const int r = tid >> 4;
        const int c = tid & 15;
        for (int il = s + SPLIT * r; il < n; il += SPLIT * 16) {
            const float qi = sq[il] - mean;
            const float sci = sc[il];
            const float xi = sp[3 * il], yi = sp[3 * il + 1], zi = sp[3 * il + 2];
            const float mxi = sm[3 * il], myi = sm[3 * il + 1], mzi = sm[3 * il + 2];
            for (int jl = c; jl < n; jl += 16) {
                if (jl == il) continue;
                float dx = xi - sp[3 * jl], dy = yi - sp[3 * jl + 1],
                      dz = zi - sp[3 * jl + 2];
                float ds0 = fmaf(dx, dx, fmaf(dy, dy, dz * dz));
                float d = sqrtf(ds0 + 1e-8f);
                float inv_d = frcp(d);
                float qj = sq[jl] - mean;
                e_c = fmaf(qi * qj * inv_d, 1.0f - __expf(-0.5f * d), e_c);
                float r6 = ds0 * ds0 * ds0;
                e_v = fmaf(sci * sc[jl], frcp(r6 + 20.0f), e_v);
                float smx = sm[3 * jl], smy = sm[3 * jl + 1], smz = sm[3 * jl + 2];
                float mdm = fmaf(mxi, smx, fmaf(myi, smy, mzi * smz));
                float mdni = fmaf(mxi, dx, fmaf(myi, dy, mzi * dz)) * inv_d;
                float mdnj = fmaf(smx, dx, fmaf(smy, dy, smz * dz)) * inv_d;
                e_d = fmaf(mdm - 3.0f * mdni * mdnj,
                           frcp(fmaf(ds0, d, 10.0f)), e_d);
            }
        }
    } else if (n > CAP) {
        // generic chunked fallback (not hit at N/NB ~128, kept for safety)
        float part = 0.f;
        for (int k = tid; k < n; k += 256) part += q_raw[st + k];
        #pragma unroll
        for (int off = 32; off > 0; off >>= 1) part += __shfl_xor(part, off);
        if ((tid & 63) == 0) red[tid >> 6] = part;
        __syncthreads();
        const float mean = (red[0] + red[1] + red[2] + red[3]) / (float)n;
        const int r = tid >> 4, c = tid & 15;
        for (int j0 = 0; j0 < n; j0 += CAP) {
            const int chunk = min(CAP, n - j0);
            __syncthreads();
            for (int k = tid; k < chunk; k += 256) {
                sq[k] = q_raw[st + j0 + k];
                sc[k] = sqc6[st + j0 + k];
            }
            for (int k = tid; k < 3 * chunk; k += 256) {
                sp[k] = pos[3 * (st + j0) + k];
                sm[k] = mu[3 * (st + j0) + k];
            }
            __syncthreads();
            for (int il = s + SPLIT * r; il < n; il += SPLIT * 16) {
                const int i = st + il;
                const float qi = q_raw[i] - mean;
                const float sci = sqc6[i];
                const float xi = pos[i * 3], yi = pos[i * 3 + 1], zi = pos[i * 3 + 2];
                const float mxi = mu[i * 3], myi = mu[i * 3 + 1], mzi = mu[i * 3 + 2];
                for (int jl = c; jl < chunk; jl += 16) {
                    if (j0 + jl == il) continue;
                    float dx = xi - sp[3 * jl], dy = yi - sp[3 * jl + 1],
                          dz = zi - sp[3 * jl + 2];
                    float ds0 = fmaf(dx, dx, fmaf(dy, dy, dz * dz));
                    float d = sqrtf(ds0 + 1e-8f);
                    float inv_d = frcp(d);
                    float qj = sq[jl] - mean;
                    e_c = fmaf(qi * qj * inv_d, 1.0f - __expf(-0.5f * d), e_c);
                    float r6 = ds0 * ds0 * ds0;
                    e_v = fmaf(sci * sc[jl], frcp(r6 + 20.0f), e_v);
                    float smx = sm[3 * jl], smy = sm[3 * jl + 1], smz = sm[3 * jl + 2];
                    float mdm = fmaf(mxi, smx, fmaf(myi, smy, mzi * smz));
                    float mdni = fmaf(mxi, dx, fmaf(myi, dy, mzi * dz)) * inv_d;
                    float mdnj = fmaf(smx, dx, fmaf(smy, dy, smz * dz)) * inv_d;
                    e_d = fmaf(mdm - 3.0f * mdni * mdnj,
                               frcp(fmaf(ds0, d, 10.0f)), e_d);
                }
            }
        }
    }

    float vv = fmaf(7.1995f, e_c, fmaf(-0.5f, e_v, 0.5f * e_d));
    #pragma unroll
    for (int off = 32; off > 0; off >>= 1) vv += __shfl_xor(vv, off);
    __syncthreads();
    if ((tid & 63) == 0) red[tid >> 6] = vv;
    __syncthreads();
    if (tid == 0) atomicAdd(out, red[0] + red[1] + red[2] + red[3]);
}

extern "C" void kernel_launch(void* const* d_in, const int* in_sizes, int n_in,
                              void* d_out, int out_size, void* d_ws, size_t ws_size,
                              hipStream_t stream) {
    const float* h0  = (const float*)d_in[0];
    const float* h1  = (const float*)d_in[1];
    const float* pos = (const float*)d_in[2];
    const int*   batch = (const int*)d_in[3];
    const float* qW1 = (const float*)d_in[4];
    const float* qb1 = (const float*)d_in[5];
    const float* qW2 = (const float*)d_in[6];
    const float* qb2 = (const float*)d_in[7];
    const float* cW1 = (const float*)d_in[8];
    const float* cb1 = (const float*)d_in[9];
    const float* cW2 = (const float*)d_in[10];
    const float* cb2 = (const float*)d_in[11];
    const float* muW = (const float*)d_in[12];
    float* out = (float*)d_out;
    const int N = in_sizes[0] / F;

    // ws layout (floats): [segstart 48 | segend 48 | pad to 128 |
    //   q_raw N | sqc6 N | mu 3N | wtq 8192 | wtc 8192]
    float* ws = (float*)d_ws;
    int* segstart = (int*)ws;
    int* segend   = (int*)(ws + 48);
    float* q_raw = ws + 128;
    float* sqc6  = q_raw + N;
    float* mu    = sqc6 + N;
    float* wtq   = mu + 3 * N;
    float* wtc   = wtq + F * H;

    k_prep<<<64, 256, 0, stream>>>(qW1, cW1, wtq, wtc, out);

    int nblk = (N + BATOMS - 1) / BATOMS;
    k_atom<<<nblk, 256, 0, stream>>>(h0, h1, batch, wtq, qb1, qW2, qb2,
                                     wtc, cb1, cW2, cb2, muW,
                                     q_raw, sqc6, mu, segstart, segend, N);
    k_pair<<<dim3(NBMOL, SPLIT), 256, 0, stream>>>(pos, q_raw, sqc6, mu,
                                                   segstart, segend, out);
}

// Round 6
// 113.418 us; speedup vs baseline: 1.2048x; 1.2048x over previous
//
#include <hip/hip_runtime.h>
#include <math.h>

#define F 128
#define H 64       // hidden width of each MLP
#define HH 32      // h per MLP block (half of H)
#define AT 64      // atoms per MLP block
#define NBMOL 48
#define CAP 256    // LDS chunk capacity in pair kernel
#define SPLIT 16   // blocks per molecule in pair kernel

__device__ __forceinline__ float silu_f(float x) {
    return x / (1.0f + __expf(-x));
}
__device__ __forceinline__ float softplus_f(float x) {
    return fmaxf(x, 0.0f) + log1pf(__expf(-fabsf(x)));
}
__device__ __forceinline__ float frcp(float x) {
    return __builtin_amdgcn_rcpf(x);
}
__device__ __forceinline__ float dot4(float4 a, float4 b) {
    return fmaf(a.x, b.x, fmaf(a.y, b.y, fmaf(a.z, b.z, a.w * b.w)));
}

// Fused per-atom kernel. Block roles by blockIdx.x:
//   [0, nmlp)           : MLP tile blocks. b -> (tile = b>>2, net = b&1,
//                         hhalf = (b>>1)&1). 64 atoms x 32 hidden per block.
//                         Both operands staged in LDS with XOR-swizzled
//                         layouts (bank-conflict-free). Output = partial
//                         sum over this h-half -> part[(net*2+hhalf)*N + i];
//                         finalize (+b2, softplus, sqrt) happens in k_pair.
//   [nmlp, nmlp+ndip)   : dipole blocks: 16 h1 rows each, coalesced float4
//                         dot with muW, 16-lane shuffle reduce.
//   last block          : segment boundaries from sorted batch + out[0]=0.
__global__ __launch_bounds__(256, 4) void k_atom(
    const float* __restrict__ h0, const float* __restrict__ h1,
    const int* __restrict__ batch,
    const float* __restrict__ qW1, const float* __restrict__ qb1,
    const float* __restrict__ qW2,
    const float* __restrict__ cW1, const float* __restrict__ cb1,
    const float* __restrict__ cW2,
    const float* __restrict__ muW,
    float* __restrict__ part,      // 4 planes of N: [net*2 + hhalf]
    float* __restrict__ mu,
    int* __restrict__ segstart, int* __restrict__ segend,
    float* __restrict__ out, int N, int nmlp, int ndip)
{
    __shared__ float4 sW4[HH * 32];   // 16 KB, row hh: f4 index XOR (hh>>1)&7
    __shared__ float4 sX4[AT * 32];   // 32 KB, row a : f4 index XOR (a>>2)&7
    __shared__ float red[4][AT];      // 1 KB epilogue reduce

    const int b = blockIdx.x;
    const int tid = threadIdx.x;

    if (b < nmlp) {
        const int tile  = b >> 2;
        const int net   = b & 1;
        const int hhalf = (b >> 1) & 1;
        const float* __restrict__ W1 = net ? cW1 : qW1;
        const float* __restrict__ b1 = net ? cb1 : qb1;
        const float* __restrict__ W2 = net ? cW2 : qW2;

        // ---- stage weights (32 h x 128 f), transposed+swizzled ----
        for (int idx = tid; idx < HH * F; idx += 256) {
            int f = idx >> 5;          // 0..127
            int hh = idx & 31;
            float val = W1[f * H + hhalf * HH + hh];
            int f4 = f >> 2, fi = f & 3;
            ((float*)&sW4[hh * 32 + (f4 ^ ((hh >> 1) & 7))])[fi] = val;
        }
        // ---- stage h0 tile (64 atoms x 128 f), swizzled, coalesced ----
        const float4* __restrict__ h0v = (const float4*)h0;
        for (int idx = tid; idx < AT * 32; idx += 256) {
            int a = idx >> 5, f4 = idx & 31;
            int row = min(tile * AT + a, N - 1);
            sX4[a * 32 + (f4 ^ ((a >> 2) & 7))] = h0v[(size_t)row * 32 + f4];
        }
        __syncthreads();

        // ---- compute: thread = (ag 0..15, hg 0..15) -> 4 atoms x 2 h ----
        const int ag = tid & 15;
        const int hg = tid >> 4;
        const int swx = ag & 7;
        const int sww = hg & 7;
        const int h0i = hhalf * HH + 2 * hg;

        float z[4][2];
        {
            float b0 = b1[h0i], b1v = b1[h0i + 1];
            #pragma unroll
            for (int j = 0; j < 4; ++j) { z[j][0] = b0; z[j][1] = b1v; }
        }

        #pragma unroll 4
        for (int f4 = 0; f4 < 32; ++f4) {
            float4 w0 = sW4[(2 * hg) * 32 + (f4 ^ sww)];
            float4 w1 = sW4[(2 * hg + 1) * 32 + (f4 ^ sww)];
            #pragma unroll
            for (int j = 0; j < 4; ++j) {
                float4 x = sX4[(4 * ag + j) * 32 + (f4 ^ swx)];
                z[j][0] += dot4(x, w0);
                z[j][1] += dot4(x, w1);
            }
        }

        const float w2a = W2[h0i], w2b = W2[h0i + 1];
        float p[4];
        #pragma unroll
        for (int j = 0; j < 4; ++j)
            p[j] = fmaf(silu_f(z[j][0]), w2a, silu_f(z[j][1]) * w2b);

        // reduce over hg: bits 4,5 of tid are in-wave; waves hold hg clusters
        #pragma unroll
        for (int j = 0; j < 4; ++j) {
            p[j] += __shfl_xor(p[j], 16);
            p[j] += __shfl_xor(p[j], 32);
        }
        const int wv = tid >> 6, lane = tid & 63;
        if (lane < 16) {
            #pragma unroll
            for (int j = 0; j < 4; ++j) red[wv][4 * lane + j] = p[j];
        }
        __syncthreads();
        if (tid < AT) {
            float s = red[0][tid] + red[1][tid] + red[2][tid] + red[3][tid];
            int atom = tile * AT + tid;
            if (atom < N) part[(size_t)(net * 2 + hhalf) * N + atom] = s;
        }
    } else if (b < nmlp + ndip) {
        // ---- dipole: 16 h1 rows per block, 16-lane slot per row ----
        const int slot = tid >> 4;
        const int l = tid & 15;
        int row = (b - nmlp) * 16 + slot;
        if (row < 3 * N) {
            const float4* rp = (const float4*)(h1 + (size_t)row * F);
            const float4* mp = (const float4*)muW;
            float pm = dot4(rp[2 * l], mp[2 * l]) +
                       dot4(rp[2 * l + 1], mp[2 * l + 1]);
            #pragma unroll
            for (int off = 1; off < 16; off <<= 1) pm += __shfl_xor(pm, off);
            if (l == 0) mu[row] = pm;
        }
    } else {
        // ---- segment boundaries + out zero ----
        if (tid == 0) out[0] = 0.0f;
        for (int i = tid; i < N; i += 256) {
            int bb = batch[i];
            if (i == 0 || batch[i - 1] != bb) segstart[bb] = i;
            if (i == N - 1 || batch[i + 1] != bb) segend[bb] = i + 1;
        }
    }
}

// Pairwise energy. Grid (NBMOL, SPLIT); block 256. Finalizes the per-atom
// MLP outputs during staging: q = p0+p1+qb2, sqc6 = sqrt(softplus(p2+p3+cb2)).
__global__ __launch_bounds__(256) void k_pair(
    const float* __restrict__ pos,
    const float* __restrict__ part,   // 4 planes of N
    const float* __restrict__ mu,
    const float* __restrict__ qb2, const float* __restrict__ cb2,
    const int* __restrict__ segstart, const int* __restrict__ segend,
    float* __restrict__ out, int N)
{
    const int b = blockIdx.x;
    const int s = blockIdx.y;
    const int tid = threadIdx.x;
    const int st = segstart[b];
    const int n = segend[b] - st;

    const float* __restrict__ p0 = part;
    const float* __restrict__ p1 = part + N;
    const float* __restrict__ p2 = part + 2 * (size_t)N;
    const float* __restrict__ p3 = part + 3 * (size_t)N;
    const float qb2v = qb2[0], cb2v = cb2[0];

    __shared__ float sq[CAP], sc[CAP], sp[3 * CAP], sm[3 * CAP];
    __shared__ float red[4];

    float e_c = 0.f, e_v = 0.f, e_d = 0.f;

    if (n > 1 && n <= CAP) {
        float partsum = 0.f;
        for (int k = tid; k < n; k += 256) {
            float qv = p0[st + k] + p1[st + k] + qb2v;
            sq[k] = qv; partsum += qv;
            sc[k] = sqrtf(softplus_f(p2[st + k] + p3[st + k] + cb2v));
        }
        for (int k = tid; k < 3 * n; k += 256) {
            sp[k] = pos[3 * st + k];
            sm[k] = mu[3 * st + k];
        }
        #pragma unroll
        for (int off = 32; off > 0; off >>= 1)
            partsum += __shfl_xor(partsum, off);
        if ((tid & 63) == 0) red[tid >> 6] = partsum;
        __syncthreads();
        const float mean = (red[0] + red[1] + red[2] + red[3]) / (float)n;

        const int r = tid >> 4;
        const int c = tid & 15;
        for (int il = s + SPLIT * r; il < n; il += SPLIT * 16) {
            const float qi = sq[il] - mean;
            const float sci = sc[il];
            const float xi = sp[3 * il], yi = sp[3 * il + 1], zi = sp[3 * il + 2];
            const float mxi = sm[3 * il], myi = sm[3 * il + 1], mzi = sm[3 * il + 2];
            for (int jl = c; jl < n; jl += 16) {
                if (jl == il) continue;
                float dx = xi - sp[3 * jl], dy = yi - sp[3 * jl + 1],
                      dz = zi - sp[3 * jl + 2];
                float ds0 = fmaf(dx, dx, fmaf(dy, dy, dz * dz));
                float d = sqrtf(ds0 + 1e-8f);
                float inv_d = frcp(d);
                float qj = sq[jl] - mean;
                e_c = fmaf(qi * qj * inv_d, 1.0f - __expf(-0.5f * d), e_c);
                float r6 = ds0 * ds0 * ds0;
                e_v = fmaf(sci * sc[jl], frcp(r6 + 20.0f), e_v);
                float smx = sm[3 * jl], smy = sm[3 * jl + 1], smz = sm[3 * jl + 2];
                float mdm = fmaf(mxi, smx, fmaf(myi, smy, mzi * smz));
                float mdni = fmaf(mxi, dx, fmaf(myi, dy, mzi * dz)) * inv_d;
                float mdnj = fmaf(smx, dx, fmaf(smy, dy, smz * dz)) * inv_d;
                e_d = fmaf(mdm - 3.0f * mdni * mdnj,
                           frcp(fmaf(ds0, d, 10.0f)), e_d);
            }
        }
    } else if (n > CAP) {
        // generic chunked fallback (not hit at N/NB ~128, kept for safety)
        float partsum = 0.f;
        for (int k = tid; k < n; k += 256)
            partsum += p0[st + k] + p1[st + k] + qb2v;
        #pragma unroll
        for (int off = 32; off > 0; off >>= 1)
            partsum += __shfl_xor(partsum, off);
        if ((tid & 63) == 0) red[tid >> 6] = partsum;
        __syncthreads();
        const float mean = (red[0] + red[1] + red[2] + red[3]) / (float)n;
        const int r = tid >> 4, c = tid & 15;
        for (int j0 = 0; j0 < n; j0 += CAP) {
            const int chunk = min(CAP, n - j0);
            __syncthreads();
            for (int k = tid; k < chunk; k += 256) {
                int j = st + j0 + k;
                sq[k] = p0[j] + p1[j] + qb2v;
                sc[k] = sqrtf(softplus_f(p2[j] + p3[j] + cb2v));
            }
            for (int k = tid; k < 3 * chunk; k += 256) {
                sp[k] = pos[3 * (st + j0) + k];
                sm[k] = mu[3 * (st + j0) + k];
            }
            __syncthreads();
            for (int il = s + SPLIT * r; il < n; il += SPLIT * 16) {
                const int i = st + il;
                const float qi = p0[i] + p1[i] + qb2v - mean;
                const float sci = sqrtf(softplus_f(p2[i] + p3[i] + cb2v));
                const float xi = pos[i * 3], yi = pos[i * 3 + 1], zi = pos[i * 3 + 2];
                const float mxi = mu[i * 3], myi = mu[i * 3 + 1], mzi = mu[i * 3 + 2];
                for (int jl = c; jl < chunk; jl += 16) {
                    if (j0 + jl == il) continue;
                    float dx = xi - sp[3 * jl], dy = yi - sp[3 * jl + 1],
                          dz = zi - sp[3 * jl + 2];
                    float ds0 = fmaf(dx, dx, fmaf(dy, dy, dz * dz));
                    float d = sqrtf(ds0 + 1e-8f);
                    float inv_d = frcp(d);
                    float qj = sq[jl] - mean;
                    e_c = fmaf(qi * qj * inv_d, 1.0f - __expf(-0.5f * d), e_c);
                    float r6 = ds0 * ds0 * ds0;
                    e_v = fmaf(sci * sc[jl], frcp(r6 + 20.0f), e_v);
                    float smx = sm[3 * jl], smy = sm[3 * jl + 1], smz = sm[3 * jl + 2];
                    float mdm = fmaf(mxi, smx, fmaf(myi, smy, mzi * smz));
                    float mdni = fmaf(mxi, dx, fmaf(myi, dy, mzi * dz)) * inv_d;
                    float mdnj = fmaf(smx, dx, fmaf(smy, dy, smz * dz)) * inv_d;
                    e_d = fmaf(mdm - 3.0f * mdni * mdnj,
                               frcp(fmaf(ds0, d, 10.0f)), e_d);
                }
            }
        }
    }

    float vv = fmaf(7.1995f, e_c, fmaf(-0.5f, e_v, 0.5f * e_d));
    #pragma unroll
    for (int off = 32; off > 0; off >>= 1) vv += __shfl_xor(vv, off);
    __syncthreads();
    if ((tid & 63) == 0) red[tid >> 6] = vv;
    __syncthreads();
    if (tid == 0) atomicAdd(out, red[0] + red[1] + red[2] + red[3]);
}

extern "C" void kernel_launch(void* const* d_in, const int* in_sizes, int n_in,
                              void* d_out, int out_size, void* d_ws, size_t ws_size,
                              hipStream_t stream) {
    const float* h0  = (const float*)d_in[0];
    const float* h1  = (const float*)d_in[1];
    const float* pos = (const float*)d_in[2];
    const int*   batch = (const int*)d_in[3];
    const float* qW1 = (const float*)d_in[4];
    const float* qb1 = (const float*)d_in[5];
    const float* qW2 = (const float*)d_in[6];
    const float* qb2 = (const float*)d_in[7];
    const float* cW1 = (const float*)d_in[8];
    const float* cb1 = (const float*)d_in[9];
    const float* cW2 = (const float*)d_in[10];
    const float* cb2 = (const float*)d_in[11];
    const float* muW = (const float*)d_in[12];
    float* out = (float*)d_out;
    const int N = in_sizes[0] / F;

    // ws layout (floats): [segstart 48 | segend 48 | pad to 128 |
    //                      part 4N | mu 3N]
    float* ws = (float*)d_ws;
    int* segstart = (int*)ws;
    int* segend   = (int*)(ws + 48);
    float* part = ws + 128;
    float* mu   = part + 4 * (size_t)N;

    const int ntile = (N + AT - 1) / AT;
    const int nmlp = 4 * ntile;                  // 2 nets x 2 h-halves
    const int ndip = (3 * N + 15) / 16;
    const int grid = nmlp + ndip + 1;

    k_atom<<<grid, 256, 0, stream>>>(h0, h1, batch, qW1, qb1, qW2,
                                     cW1, cb1, cW2, muW,
                                     part, mu, segstart, segend, out,
                                     N, nmlp, ndip);
    k_pair<<<dim3(NBMOL, SPLIT), 256, 0, stream>>>(pos, part, mu, qb2, cb2,
                                                   segstart, segend, out, N);
}